// Round 3
// baseline (630.844 us; speedup 1.0000x reference)
//
#include <hip/hip_runtime.h>
#include <stdint.h>

// InstanceSampling: greedy per-class radius suppression (exact reference semantics).
// B=2, N=8192, C=3, L=16384. RADII = {0.5,0.6,0.7}; radius of pick #i is
// RADII[label of sorted slot i] (reference quirk: indexed by pick ORDINAL).
//
// k1 init+keys -> k2 O(L^2) rank sort -> g2 scan -> g3 cell scatter ->
// k3 greedy (single block; 128-wide consumed windows, register-prefetched,
// wave0 resolves window t-1 while waves 1..15 apply suppression of batch t-1)
// -> k4 out.

#define L_TOT 16384
#define NPT   8192

__device__ __forceinline__ int cellco(float v) {
    int c = (int)floorf((v + 6.4f) * 1.25f);   // cell size 0.8 >= max radius 0.7
    return c < 0 ? 0 : (c > 15 ? 15 : c);
}
__device__ __forceinline__ float d2f(float ax, float ay, float az,
                                     float bx, float by, float bz) {
    float dx = __fsub_rn(ax, bx), dy = __fsub_rn(ay, by), dz = __fsub_rn(az, bz);
    return __fadd_rn(__fadd_rn(__fmul_rn(dx, dx), __fmul_rn(dy, dy)), __fmul_rn(dz, dz));
}

// ---------------- k1: init + per-point keys ----------------
__global__ void k1_keys(const float* __restrict__ cls, uint64_t* __restrict__ keys,
                        uint8_t* __restrict__ umeta, uint16_t* __restrict__ sample,
                        int* __restrict__ cellcnt) {
    int l = blockIdx.x * blockDim.x + threadIdx.x;
    if (l >= L_TOT) return;
    ((uint32_t*)sample)[l] = 0;                  // zero 2*L u16
    if (l < 8192) cellcnt[l] = 0;
    float c0 = cls[l * 3 + 0], c1 = cls[l * 3 + 1], c2 = cls[l * 3 + 2];
    float m = c0; int lab = 0;
    if (c1 > m) { m = c1; lab = 1; }   // strict > : first-max, matches jnp.argmax
    if (c2 > m) { m = c2; lab = 2; }
    int valid = (m >= 0.0f) ? 1 : 0;   // sigmoid(m) >= 0.5  <=>  m >= 0
    float keyf = valid ? m : -__builtin_inff();
    uint32_t u = __float_as_uint(keyf);
    uint32_t o = (u & 0x80000000u) ? ~u : (u | 0x80000000u); // order-preserving map
    keys[l] = ((uint64_t)(~o) << 32) | (uint32_t)l;          // asc == desc score, stable
    umeta[l] = (uint8_t)(lab | (valid << 2));
}

// ---------------- k2: O(L^2) rank sort + build sorted arrays + cell counts ----
__global__ void __launch_bounds__(256) k2_sort(
    const uint64_t* __restrict__ keys, const uint8_t* __restrict__ umeta,
    const float* __restrict__ xyz,
    float4* __restrict__ spts, uint8_t* __restrict__ slab, uint16_t* __restrict__ sorder,
    int* __restrict__ cellcnt) {
    __shared__ uint64_t tile[2048];
    __shared__ int psum[256];
    const int t = threadIdx.x;
    const int elem = t & 31, part = t >> 5;
    const int l = blockIdx.x * 32 + elem;
    const uint64_t myk = keys[l];
    int cnt = 0;
    for (int t0 = 0; t0 < L_TOT; t0 += 2048) {
        for (int j = t; j < 2048; j += 256) tile[j] = keys[t0 + j];
        __syncthreads();
        const int b0 = part * 256;
        #pragma unroll 4
        for (int j = 0; j < 256; ++j) cnt += (tile[b0 + j] < myk) ? 1 : 0;
        __syncthreads();
    }
    psum[t] = cnt;
    __syncthreads();
    if (t < 32) {
        int rank = 0;
        #pragma unroll
        for (int q = 0; q < 8; ++q) rank += psum[q * 32 + t];
        const int ll = blockIdx.x * 32 + t;
        int b = ll >> 13, p = ll & (NPT - 1);
        const float* src = xyz + ((size_t)(b * NPT + p)) * 3;
        float x = src[0], y = src[1], z = src[2];
        uint8_t mt = umeta[ll];
        int lab = mt & 3, valid = (mt >> 2) & 1;
        float4 v; v.x = x; v.y = y; v.z = z;
        v.w = __uint_as_float((uint32_t)(b | (valid << 1)));
        spts[rank] = v;
        slab[rank] = (uint8_t)lab;
        sorder[rank] = (uint16_t)ll;
        if (valid) {
            int cl = (b << 12) | (cellco(z) << 8) | (cellco(y) << 4) | cellco(x);
            atomicAdd(&cellcnt[cl], 1);
        }
    }
}

// ---------------- g2: exclusive scan (8193 entries) + zero counts for reuse --
__global__ void g2_scan(int* __restrict__ cellcnt, int* __restrict__ cellstart) {
    __shared__ int part[256];
    __shared__ int poff[256];
    int t = threadIdx.x;
    int base = t * 32;
    int loc[32];
    int s = 0;
    for (int k = 0; k < 32; ++k) { loc[k] = cellcnt[base + k]; s += loc[k]; }
    part[t] = s;
    __syncthreads();
    if (t == 0) {
        int run = 0;
        for (int q = 0; q < 256; ++q) { poff[q] = run; run += part[q]; }
    }
    __syncthreads();
    int run = poff[t];
    for (int k = 0; k < 32; ++k) {
        cellstart[base + k] = run; run += loc[k];
        cellcnt[base + k] = 0;               // reuse as fill counters in g3
    }
    if (t == 255) cellstart[8192] = run;     // sentinel = V (valid count)
}

// ---------------- g3: scatter coords into cell-ordered float4 list ----------
__global__ void g3_scatter(const float4* __restrict__ spts, const int* __restrict__ cellstart,
                           int* __restrict__ cellfill, float4* __restrict__ cellxyz) {
    int pos = blockIdx.x * blockDim.x + threadIdx.x;
    if (pos >= L_TOT) return;
    float4 v = spts[pos];
    uint32_t w = __float_as_uint(v.w);
    if (!(w & 2u)) return;                   // invalid
    int b = (int)(w & 1u);
    int cl = (b << 12) | (cellco(v.z) << 8) | (cellco(v.y) << 4) | cellco(v.x);
    int slot = atomicAdd(&cellfill[cl], 1);
    float4 o; o.x = v.x; o.y = v.y; o.z = v.z; o.w = __uint_as_float((uint32_t)pos);
    cellxyz[cellstart[cl] + slot] = o;
}

// ---------------- k3: consumed-window pipelined greedy (single block) --------
// Phase ph: wave0 resolves window gathered at ph-1 (coords prefetched in regs)
// -> pick batch pk[ph&3]; then gathers window ph (consuming its rem bits) and
// issues next prefetch. Waves 1..15 apply suppression of pk[(ph-1)&3].
// Patch at resolve covers the 2 possibly-unapplied batches. 1 barrier/phase.
__global__ void __launch_bounds__(1024) k3_greedy(
    const float4* __restrict__ spts, const uint8_t* __restrict__ slab,
    const uint16_t* __restrict__ sorder,
    const int* __restrict__ cellstart, const float4* __restrict__ cellxyz,
    uint16_t* __restrict__ sample) {
    __shared__ uint32_t rem[512];            // remaining bitmask by sorted position
    __shared__ uint16_t cs16[8193];          // cellstart (u16), sentinel at [8192]
    __shared__ float4   pkd[4][128];         // x,y,z,r2 pick ring
    __shared__ int      pkb[4][128];         // pick batch ring
    __shared__ int      pkn[4];
    __shared__ int      win_pos[128];
    __shared__ int      s_done;

    const int t = threadIdx.x;
    const int V = cellstart[8192];
    for (int j = t; j < 8193; j += 1024) cs16[j] = (uint16_t)cellstart[j];
    for (int w = t; w < 512; w += 1024) {
        int lo = w * 32;
        uint32_t m;
        if (V >= lo + 32) m = 0xFFFFFFFFu;
        else if (V <= lo) m = 0u;
        else m = (1u << (V - lo)) - 1u;
        rem[w] = m;                          // valid points occupy positions [0, V)
    }
    if (t < 4) pkn[t] = 0;
    if (t == 0) s_done = 0;
    __syncthreads();

    // wave0 persistent window state (2 candidates per lane)
    float4 cv0 = make_float4(0,0,0,0), cv1 = make_float4(0,0,0,0);
    int cord0 = 0, cord1 = 0, cb0 = 0, cb1 = 0;
    float cr0 = 0.f, cr1 = 0.f;
    int ii = 0, nwin = 0;

    auto gather = [&]() {
        uint32_t wv[8]; int cnt = 0;
        #pragma unroll
        for (int q = 0; q < 8; ++q) {
            wv[q] = ((volatile uint32_t*)rem)[t * 8 + q];
            cnt += __popc(wv[q]);
        }
        int pre = cnt;
        #pragma unroll
        for (int off = 1; off < 64; off <<= 1) {
            int nb = __shfl_up(pre, off);
            if (t >= off) pre += nb;
        }
        const int total = __shfl(pre, 63);
        if (total == 0) { if (t == 0) s_done = 1; nwin = 0; return; }
        int r = pre - cnt;                   // exclusive prefix in bit order
        uint32_t clr[8];
        #pragma unroll
        for (int q = 0; q < 8; ++q) clr[q] = 0u;
        if (r < 128) {
            #pragma unroll
            for (int q = 0; q < 8; ++q) {
                if (r >= 128) break;
                uint32_t m = wv[q];
                while (m && r < 128) {
                    uint32_t bit = m & (~m + 1u);
                    int b = __builtin_ctz(m);
                    m &= m - 1u;
                    win_pos[r] = (t * 8 + q) * 32 + b;
                    clr[q] |= bit;
                    ++r;
                }
            }
        }
        // consume: gathered candidates leave rem forever
        #pragma unroll
        for (int q = 0; q < 8; ++q)
            if (clr[q]) atomicAnd(&rem[t * 8 + q], ~clr[q]);
        for (int z = total + t; z < 128; z += 64) win_pos[z] = 0;
        __builtin_amdgcn_wave_barrier();
        asm volatile("s_waitcnt lgkmcnt(0)" ::: "memory");
        __builtin_amdgcn_wave_barrier();
        nwin = total < 128 ? total : 128;
        int p0 = win_pos[t], p1 = win_pos[64 + t];
        cv0 = spts[p0]; cv1 = spts[p1];          // in flight across the barrier
        cord0 = (int)sorder[p0]; cord1 = (int)sorder[p1];
        cb0 = cord0 >> 13; cb1 = cord1 >> 13;
        int o0 = ii + t;       o0 = o0 > (L_TOT - 1) ? (L_TOT - 1) : o0;
        int o1 = ii + 64 + t;  o1 = o1 > (L_TOT - 1) ? (L_TOT - 1) : o1;
        int l0 = slab[o0], l1 = slab[o1];
        float rr0 = (l0 == 0) ? 0.5f : ((l0 == 1) ? 0.6f : 0.7f);
        float rr1 = (l1 == 0) ? 0.5f : ((l1 == 1) ? 0.6f : 0.7f);
        cr0 = __fmul_rn(rr0, rr0); cr1 = __fmul_rn(rr1, rr1);
    };

    if (t < 64) gather();                    // prologue: window 0
    __syncthreads();

    for (int ph = 0; ph < 4096; ++ph) {
        const int cur = ph & 3, prev1 = (ph + 3) & 3, prev2 = (ph + 2) & 3;
        if (t < 64) {
            // ---- wave0: resolve previously gathered window ----
            int np = 0;
            if (nwin > 0) {
                bool a0 = (t < nwin), a1 = (64 + t < nwin);
                // patch vs the 2 batches whose suppression may be unapplied
                #pragma unroll 1
                for (int rs = 0; rs < 2; ++rs) {
                    const int ring = (rs == 0) ? prev1 : prev2;
                    const int m = pkn[ring];
                    for (int j = 0; j < m; ++j) {
                        float4 pk = pkd[ring][j];
                        int pb = pkb[ring][j];
                        if (a0 && cb0 == pb &&
                            d2f(cv0.x, cv0.y, cv0.z, pk.x, pk.y, pk.z) <= pk.w) a0 = false;
                        if (a1 && cb1 == pb &&
                            d2f(cv1.x, cv1.y, cv1.z, pk.x, pk.y, pk.z) <= pk.w) a1 = false;
                    }
                }
                unsigned long long am0 = __ballot(a0 ? 1 : 0);
                unsigned long long am1 = __ballot(a1 ? 1 : 0);
                while (am0 | am1) {
                    const int js = am0 ? 0 : 1;
                    const int jl = am0 ? (int)__builtin_ctzll(am0)
                                       : (int)__builtin_ctzll(am1);
                    float px = __shfl(js ? cv1.x : cv0.x, jl);
                    float py = __shfl(js ? cv1.y : cv0.y, jl);
                    float pz = __shfl(js ? cv1.z : cv0.z, jl);
                    int   pb = __shfl(js ? cb1 : cb0, jl);
                    float r2 = __shfl((np & 64) ? cr1 : cr0, np & 63);
                    if (t == jl) {
                        int    b_ = js ? cb1 : cb0;
                        int    o_ = js ? cord1 : cord0;
                        float  x_ = js ? cv1.x : cv0.x;
                        float  y_ = js ? cv1.y : cv0.y;
                        float  z_ = js ? cv1.z : cv0.z;
                        pkd[cur][np] = make_float4(x_, y_, z_, r2);
                        pkb[cur][np] = b_;
                        sample[b_ * L_TOT + ii + np] = (uint16_t)(o_ & (NPT - 1));
                    }
                    if (a0 && cb0 == pb && d2f(cv0.x, cv0.y, cv0.z, px, py, pz) <= r2) a0 = false;
                    if (a1 && cb1 == pb && d2f(cv1.x, cv1.y, cv1.z, px, py, pz) <= r2) a1 = false;
                    ++np;
                    am0 = __ballot(a0 ? 1 : 0);
                    am1 = __ballot(a1 ? 1 : 0);
                }
                ii += np;
            }
            if (t == 0) pkn[cur] = np;
            // ---- gather next window + issue prefetch loads ----
            gather();
        } else {
            // ---- waves 1..15: apply suppression of batch ph-1 ----
            const int np = pkn[prev1];
            if (np > 0) {
                const int tid = t - 64;                  // 0..959
                const int ntask = np * 216;              // 27 cells x 8-way split
                for (int task = tid; task < ntask; task += 960) {
                    int sub = task & 7;
                    int pc = task >> 3;
                    int p = pc / 27;
                    int c = pc - p * 27;
                    float4 pv = pkd[prev1][p];
                    int pb_ = pkb[prev1][p];
                    float r2 = pv.w;
                    int cx = cellco(pv.x) + (c % 3) - 1;
                    int cy = cellco(pv.y) + ((c / 3) % 3) - 1;
                    int cz = cellco(pv.z) + (c / 9) - 1;
                    if ((unsigned)cx > 15u || (unsigned)cy > 15u || (unsigned)cz > 15u) continue;
                    // conservative cell-box cull (margin >> any rounding diff)
                    float lox = -6.4f + 0.8f * cx, hix = lox + 0.8f;
                    float loy = -6.4f + 0.8f * cy, hiy = loy + 0.8f;
                    float loz = -6.4f + 0.8f * cz, hiz = loz + 0.8f;
                    if (cx == 0) lox = -1e30f;  if (cx == 15) hix = 1e30f;
                    if (cy == 0) loy = -1e30f;  if (cy == 15) hiy = 1e30f;
                    if (cz == 0) loz = -1e30f;  if (cz == 15) hiz = 1e30f;
                    float dx = fmaxf(fmaxf(lox - pv.x, pv.x - hix), 0.0f);
                    float dy = fmaxf(fmaxf(loy - pv.y, pv.y - hiy), 0.0f);
                    float dz = fmaxf(fmaxf(loz - pv.z, pv.z - hiz), 0.0f);
                    if (dx * dx + dy * dy + dz * dz > r2 + 0.02f) continue;
                    int st = (int)cs16[(pb_ << 12) | (cz << 8) | (cy << 4) | cx];
                    int en = (int)cs16[((pb_ << 12) | (cz << 8) | (cy << 4) | cx) + 1];
                    for (int k = st + sub; k < en; k += 8) {
                        float4 q = cellxyz[k];
                        float d2 = d2f(q.x, q.y, q.z, pv.x, pv.y, pv.z);
                        if (d2 <= r2) {
                            uint32_t qp = __float_as_uint(q.w);
                            atomicAnd(&rem[qp >> 5], ~(1u << (qp & 31)));
                        }
                    }
                }
            }
        }
        __syncthreads();
        if (s_done) break;
    }
}

// ---------------- k4: write outputs ----------------
__global__ void k4_out(const float* __restrict__ xyz, const uint16_t* __restrict__ sample,
                       float* __restrict__ out) {
    int s = blockIdx.x * blockDim.x + threadIdx.x;
    if (s >= 2 * L_TOT) return;
    int idx = (int)sample[s];
    int b = s >> 14;
    const float* src = xyz + ((size_t)(b * NPT + idx)) * 3;
    float* dst = out + (size_t)s * 3;
    dst[0] = src[0]; dst[1] = src[1]; dst[2] = src[2];
    out[3 * 2 * L_TOT + s] = (float)idx;   // sample_idx as float32 values
}

extern "C" void kernel_launch(void* const* d_in, const int* in_sizes, int n_in,
                              void* d_out, int out_size, void* d_ws, size_t ws_size,
                              hipStream_t stream) {
    const float* xyz = (const float*)d_in[0];
    const float* cls = (const float*)d_in[1];
    float* out = (float*)d_out;
    char* ws = (char*)d_ws;
    // layout:
    float4*   spts    = (float4*)  (ws + 0);        // 262144
    uint8_t*  slab    = (uint8_t*) (ws + 262144);   // 16384
    uint16_t* sorder  = (uint16_t*)(ws + 278528);   // 32768
    int*      cellcnt = (int*)     (ws + 311296);   // 32768 (reused as fill counters)
    int*      cellst  = (int*)     (ws + 344064);   // 36864 (8193 ints + pad)
    float4*   cellxyz = (float4*)  (ws + 380928);   // 262144
    uint64_t* keys    = (uint64_t*)(ws + 380928);   // alias: dead after k2
    uint8_t*  umeta   = (uint8_t*) (ws + 512000);   // alias: dead after k2
    uint16_t* sample  = (uint16_t*)(ws + 643072);   // 65536

    k1_keys   <<<64,  256, 0, stream>>>(cls, keys, umeta, sample, cellcnt);
    k2_sort   <<<512, 256, 0, stream>>>(keys, umeta, xyz, spts, slab, sorder, cellcnt);
    g2_scan   <<<1,   256, 0, stream>>>(cellcnt, cellst);
    g3_scatter<<<64,  256, 0, stream>>>(spts, cellst, cellcnt, cellxyz);
    k3_greedy <<<1,  1024, 0, stream>>>(spts, slab, sorder, cellst, cellxyz, sample);
    k4_out    <<<128, 256, 0, stream>>>(xyz, sample, out);
}